// Round 4
// baseline (25.581 us; speedup 1.0000x reference)
//
#include <hip/hip_runtime.h>

// ROI pooling (bilinear resize of each ROI to 7x7), matching the JAX reference.
// image: (1, 200, 200, 512) f32 NHWC; rois: (1, 300, 4) f32 (x,y,w,h); out: (1,300,7,7,512) f32.
//
// R4: Morton-sort ROIs by spatial center (one tiny bitonic-sort block into d_ws),
// then chunk the SORTED cell space across XCDs. Each XCD then reads a compact
// ~1/8 region of the image instead of ~37 random ROIs, cutting per-XCD-duplicated
// HBM fetches. Main kernel unchanged otherwise: 2 cells/block, 8 loads in flight,
// nontemporal output stores.

#define POOL   7
#define N_ROI  300
#define IMG_W  200
#define CH4    128           // 512 channels / 4 = float4 groups per pixel
#define NCELL  (N_ROI * POOL * POOL)   // 14700
#define NBLK   (NCELL / 2)             // 7350
#define NXCD   8
#define SORTN  512

typedef float f4 __attribute__((ext_vector_type(4)));

// ---------------- ROI spatial sort (single block, bitonic over 512) ----------
__global__ __launch_bounds__(SORTN) void sort_rois_kernel(
        const float* __restrict__ rois,
        unsigned* __restrict__ perm) {
    __shared__ unsigned key[SORTN];
    const int t = threadIdx.x;
    unsigned k = 0xFFFFFFFFu;                 // pad sorts to the end
    if (t < N_ROI) {
        const f4 rv = ((const f4*)rois)[t];
        const int cx = (int)rv.x + ((int)rv.z >> 1);
        const int cy = (int)rv.y + ((int)rv.w >> 1);
        unsigned m = 0;
        #pragma unroll
        for (int i = 0; i < 8; ++i)
            m |= (((unsigned)(cx >> i) & 1u) << (2 * i))
               | (((unsigned)(cy >> i) & 1u) << (2 * i + 1));
        k = (m << 9) | (unsigned)t;           // 16-bit Morton | 9-bit index
    }
    key[t] = k;
    __syncthreads();
    for (int sz = 2; sz <= SORTN; sz <<= 1) {
        for (int st = sz >> 1; st > 0; st >>= 1) {
            const int j = t ^ st;
            if (j > t) {
                const unsigned a = key[t], b = key[j];
                const bool up = ((t & sz) == 0);
                if ((a > b) == up) { key[t] = b; key[j] = a; }
            }
            __syncthreads();
        }
    }
    if (t < N_ROI) perm[t] = key[t] & 0x1FFu;
}

// ---------------- main ROI pooling ------------------------------------------
struct Cell {
    int c00, c01, c10, c11;   // float4 base indices of the 4 corner pixels
    int outc;                 // float4 base index of the output cell
    float w00, w01, w10, w11;
};

__device__ inline Cell decode_cell(const f4* __restrict__ rois4,
                                   const unsigned* __restrict__ perm, int b) {
    const int q  = b % POOL;
    const int tt = b / POOL;
    const int p  = tt % POOL;
    const int rs = tt / POOL;                     // sorted rank
    const int r  = perm ? (int)perm[rs] : rs;     // original ROI index

    const f4 rv = rois4[r];
    const int x = (int)rv.x;
    const int y = (int)rv.y;
    const int w = (int)rv.z;
    const int h = (int)rv.w;

    // Legacy resize arithmetic, replicated in f32 exactly as the reference.
    const float sy = (float)p * ((float)h / 7.0f);
    const int y0 = (int)floorf(sy);
    const int y1 = min(y0 + 1, h - 1);
    const float fy = sy - (float)y0;

    const float sx = (float)q * ((float)w / 7.0f);
    const int x0 = (int)floorf(sx);
    const int x1 = min(x0 + 1, w - 1);
    const float fx = sx - (float)x0;

    const int row0 = (y + y0) * IMG_W;
    const int row1 = (y + y1) * IMG_W;

    Cell cl;
    cl.c00 = (row0 + x + x0) * CH4;
    cl.c01 = (row0 + x + x1) * CH4;
    cl.c10 = (row1 + x + x0) * CH4;
    cl.c11 = (row1 + x + x1) * CH4;
    cl.outc = (r * (POOL * POOL) + (b - rs * (POOL * POOL))) * CH4;
    cl.w00 = (1.0f - fy) * (1.0f - fx);
    cl.w01 = (1.0f - fy) * fx;
    cl.w10 = fy * (1.0f - fx);
    cl.w11 = fy * fx;
    return cl;
}

__device__ inline f4 blend(f4 a, f4 b, f4 c, f4 d,
                           float wa, float wb, float wc, float wd) {
    return a * wa + b * wb + c * wc + d * wd;
}

__global__ __launch_bounds__(CH4) void roi_pool_kernel(
        const float* __restrict__ image,
        const float* __restrict__ rois,
        const unsigned* __restrict__ perm,   // may be nullptr (identity)
        float* __restrict__ out) {
    // Bijective chunked XCD swizzle over SORTED cell space: consecutive sorted
    // cells (spatially clustered ROIs) land on the same XCD's L2.
    const int bid = blockIdx.x;
    const int qc = NBLK / NXCD;        // 918
    const int rm = NBLK % NXCD;        // 6
    const int xcd = bid % NXCD;
    const int idx = bid / NXCD;
    const int blk = (xcd < rm ? xcd * (qc + 1)
                              : rm * (qc + 1) + (xcd - rm) * qc) + idx;

    const int c = threadIdx.x;          // 0..127 (float4 channel group)
    const f4* __restrict__ img4  = (const f4*)image;
    const f4* __restrict__ rois4 = (const f4*)rois;
    f4* __restrict__ out4 = (f4*)out;

    const int b0 = blk * 2;
    const int b1 = b0 + 1;

    const Cell cA = decode_cell(rois4, perm, b0);
    const Cell cB = decode_cell(rois4, perm, b1);

    // Issue all 8 loads before any blend — 8 outstanding VMEM ops per thread.
    const f4 a00 = img4[cA.c00 + c];
    const f4 a01 = img4[cA.c01 + c];
    const f4 a10 = img4[cA.c10 + c];
    const f4 a11 = img4[cA.c11 + c];
    const f4 b00 = img4[cB.c00 + c];
    const f4 b01 = img4[cB.c01 + c];
    const f4 b10 = img4[cB.c10 + c];
    const f4 b11 = img4[cB.c11 + c];

    const f4 oA = blend(a00, a01, a10, a11, cA.w00, cA.w01, cA.w10, cA.w11);
    const f4 oB = blend(b00, b01, b10, b11, cB.w00, cB.w01, cB.w10, cB.w11);

    // Output is write-once/never-read: nontemporal to spare L2/L3 for the image.
    __builtin_nontemporal_store(oA, &out4[cA.outc + c]);
    __builtin_nontemporal_store(oB, &out4[cB.outc + c]);
}

extern "C" void kernel_launch(void* const* d_in, const int* in_sizes, int n_in,
                              void* d_out, int out_size, void* d_ws, size_t ws_size,
                              hipStream_t stream) {
    const float* image = (const float*)d_in[0];
    const float* rois  = (const float*)d_in[1];
    float* out = (float*)d_out;

    if (ws_size >= N_ROI * sizeof(unsigned)) {
        unsigned* perm = (unsigned*)d_ws;
        sort_rois_kernel<<<1, SORTN, 0, stream>>>(rois, perm);
        roi_pool_kernel<<<NBLK, CH4, 0, stream>>>(image, rois, perm, out);
    } else {
        roi_pool_kernel<<<NBLK, CH4, 0, stream>>>(image, rois, nullptr, out);
    }
}

// Round 5
// 22.098 us; speedup vs baseline: 1.1576x; 1.1576x over previous
//
#include <hip/hip_runtime.h>

// ROI pooling (bilinear resize of each ROI to 7x7), matching the JAX reference.
// image: (1, 200, 200, 512) f32 NHWC; rois: (1, 300, 4) f32 (x,y,w,h); out: (1,300,7,7,512) f32.
//
// R5: revert R4's sort (cost > gain; L3 is shared/memory-side so cross-XCD pixel
// reuse never hits HBM anyway). R3 structure, but 256-thread blocks doing 4 cells
// each (each 128-lane half does 2 cells, 8 loads in flight per thread) -> 3675
// blocks instead of 14700: less block-dispatch overhead, same per-thread ILP.

#define POOL   7
#define N_ROI  300
#define IMG_W  200
#define CH4    128           // 512 channels / 4 = float4 groups per pixel
#define NCELL  (N_ROI * POOL * POOL)   // 14700
#define CELLS_PER_BLK 4
#define NBLK   (NCELL / CELLS_PER_BLK) // 3675
#define NXCD   8

typedef float f4 __attribute__((ext_vector_type(4)));

struct Cell {
    int c00, c01, c10, c11;   // float4 base indices of the 4 corner pixels
    float w00, w01, w10, w11;
};

__device__ inline Cell decode_cell(const f4* __restrict__ rois4, int b) {
    const int q = b % POOL;
    const int t = b / POOL;
    const int p = t % POOL;
    const int r = t / POOL;

    const f4 rv = rois4[r];
    const int x = (int)rv.x;
    const int y = (int)rv.y;
    const int w = (int)rv.z;
    const int h = (int)rv.w;

    // Legacy resize arithmetic, replicated in f32 exactly as the reference.
    const float sy = (float)p * ((float)h / 7.0f);
    const int y0 = (int)floorf(sy);
    const int y1 = min(y0 + 1, h - 1);
    const float fy = sy - (float)y0;

    const float sx = (float)q * ((float)w / 7.0f);
    const int x0 = (int)floorf(sx);
    const int x1 = min(x0 + 1, w - 1);
    const float fx = sx - (float)x0;

    const int row0 = (y + y0) * IMG_W;
    const int row1 = (y + y1) * IMG_W;

    Cell cl;
    cl.c00 = (row0 + x + x0) * CH4;
    cl.c01 = (row0 + x + x1) * CH4;
    cl.c10 = (row1 + x + x0) * CH4;
    cl.c11 = (row1 + x + x1) * CH4;
    cl.w00 = (1.0f - fy) * (1.0f - fx);
    cl.w01 = (1.0f - fy) * fx;
    cl.w10 = fy * (1.0f - fx);
    cl.w11 = fy * fx;
    return cl;
}

__device__ inline f4 blend(f4 a, f4 b, f4 c, f4 d,
                           float wa, float wb, float wc, float wd) {
    return a * wa + b * wb + c * wc + d * wd;
}

__global__ __launch_bounds__(256) void roi_pool_kernel(
        const float* __restrict__ image,
        const float* __restrict__ rois,
        float* __restrict__ out) {
    // Bijective chunked XCD swizzle: contiguous chunks of block-space per XCD
    // so a ROI's blocks (overlapping pixel reads) share one L2.
    const int bid = blockIdx.x;
    const int qc = NBLK / NXCD;
    const int rm = NBLK % NXCD;
    const int xcd = bid % NXCD;
    const int idx = bid / NXCD;
    const int blk = (xcd < rm ? xcd * (qc + 1)
                              : rm * (qc + 1) + (xcd - rm) * qc) + idx;

    const int c    = threadIdx.x & (CH4 - 1);   // 0..127 (float4 channel group)
    const int half = threadIdx.x >> 7;          // 0/1: which cell pair

    const f4* __restrict__ img4  = (const f4*)image;
    const f4* __restrict__ rois4 = (const f4*)rois;
    f4* __restrict__ out4 = (f4*)out;

    const int b0 = blk * CELLS_PER_BLK + half * 2;
    const int b1 = b0 + 1;

    const Cell cA = decode_cell(rois4, b0);
    const Cell cB = decode_cell(rois4, b1);

    // Issue all 8 loads before any blend — 8 outstanding VMEM ops per thread.
    const f4 a00 = img4[cA.c00 + c];
    const f4 a01 = img4[cA.c01 + c];
    const f4 a10 = img4[cA.c10 + c];
    const f4 a11 = img4[cA.c11 + c];
    const f4 b00 = img4[cB.c00 + c];
    const f4 b01 = img4[cB.c01 + c];
    const f4 b10 = img4[cB.c10 + c];
    const f4 b11 = img4[cB.c11 + c];

    const f4 oA = blend(a00, a01, a10, a11, cA.w00, cA.w01, cA.w10, cA.w11);
    const f4 oB = blend(b00, b01, b10, b11, cB.w00, cB.w01, cB.w10, cB.w11);

    // Output is write-once/never-read: nontemporal to spare L2/L3 for the image.
    __builtin_nontemporal_store(oA, &out4[b0 * CH4 + c]);
    __builtin_nontemporal_store(oB, &out4[b1 * CH4 + c]);
}

extern "C" void kernel_launch(void* const* d_in, const int* in_sizes, int n_in,
                              void* d_out, int out_size, void* d_ws, size_t ws_size,
                              hipStream_t stream) {
    const float* image = (const float*)d_in[0];
    const float* rois  = (const float*)d_in[1];
    float* out = (float*)d_out;

    roi_pool_kernel<<<NBLK, 256, 0, stream>>>(image, rois, out);
}

// Round 6
// 19.808 us; speedup vs baseline: 1.2915x; 1.1156x over previous
//
#include <hip/hip_runtime.h>

// ROI pooling (bilinear resize of each ROI to 7x7), matching the JAX reference.
// image: (1, 200, 200, 512) f32 NHWC; rois: (1, 300, 4) f32 (x,y,w,h); out: (1,300,7,7,512) f32.
//
// R6: R5 structure + zero-weight corner collapse: when fx==0 the x1 column has
// weight exactly 0 (legacy-resize lerp collapses), so point x1 at x0 instead of
// fetching a never-used pixel (2KB saved per occurrence; always true at q==0/p==0).
// Numerically identical: rows[x0]*(1-0) + rows[x0]*0 == rows[x0].

#define POOL   7
#define N_ROI  300
#define IMG_W  200
#define CH4    128           // 512 channels / 4 = float4 groups per pixel
#define NCELL  (N_ROI * POOL * POOL)   // 14700
#define CELLS_PER_BLK 4
#define NBLK   (NCELL / CELLS_PER_BLK) // 3675
#define NXCD   8

typedef float f4 __attribute__((ext_vector_type(4)));

struct Cell {
    int c00, c01, c10, c11;   // float4 base indices of the 4 corner pixels
    float w00, w01, w10, w11;
};

__device__ inline Cell decode_cell(const f4* __restrict__ rois4, int b) {
    const int q = b % POOL;
    const int t = b / POOL;
    const int p = t % POOL;
    const int r = t / POOL;

    const f4 rv = rois4[r];
    const int x = (int)rv.x;
    const int y = (int)rv.y;
    const int w = (int)rv.z;
    const int h = (int)rv.w;

    // Legacy resize arithmetic, replicated in f32 exactly as the reference.
    const float sy = (float)p * ((float)h / 7.0f);
    const int y0 = (int)floorf(sy);
    const float fy = sy - (float)y0;
    // fy==0 -> y1's weight is exactly 0; collapse to y0 to avoid fetching a
    // pixel that contributes nothing (it may be touched by no other cell).
    const int y1 = (fy == 0.0f) ? y0 : min(y0 + 1, h - 1);

    const float sx = (float)q * ((float)w / 7.0f);
    const int x0 = (int)floorf(sx);
    const float fx = sx - (float)x0;
    const int x1 = (fx == 0.0f) ? x0 : min(x0 + 1, w - 1);

    const int row0 = (y + y0) * IMG_W;
    const int row1 = (y + y1) * IMG_W;

    Cell cl;
    cl.c00 = (row0 + x + x0) * CH4;
    cl.c01 = (row0 + x + x1) * CH4;
    cl.c10 = (row1 + x + x0) * CH4;
    cl.c11 = (row1 + x + x1) * CH4;
    cl.w00 = (1.0f - fy) * (1.0f - fx);
    cl.w01 = (1.0f - fy) * fx;
    cl.w10 = fy * (1.0f - fx);
    cl.w11 = fy * fx;
    return cl;
}

__device__ inline f4 blend(f4 a, f4 b, f4 c, f4 d,
                           float wa, float wb, float wc, float wd) {
    return a * wa + b * wb + c * wc + d * wd;
}

__global__ __launch_bounds__(256) void roi_pool_kernel(
        const float* __restrict__ image,
        const float* __restrict__ rois,
        float* __restrict__ out) {
    // Bijective chunked XCD swizzle: contiguous chunks of block-space per XCD
    // so a ROI's blocks (overlapping pixel reads) share one L2.
    const int bid = blockIdx.x;
    const int qc = NBLK / NXCD;
    const int rm = NBLK % NXCD;
    const int xcd = bid % NXCD;
    const int idx = bid / NXCD;
    const int blk = (xcd < rm ? xcd * (qc + 1)
                              : rm * (qc + 1) + (xcd - rm) * qc) + idx;

    const int c    = threadIdx.x & (CH4 - 1);   // 0..127 (float4 channel group)
    const int half = threadIdx.x >> 7;          // 0/1: which cell pair

    const f4* __restrict__ img4  = (const f4*)image;
    const f4* __restrict__ rois4 = (const f4*)rois;
    f4* __restrict__ out4 = (f4*)out;

    const int b0 = blk * CELLS_PER_BLK + half * 2;
    const int b1 = b0 + 1;

    const Cell cA = decode_cell(rois4, b0);
    const Cell cB = decode_cell(rois4, b1);

    // Issue all 8 loads before any blend — 8 outstanding VMEM ops per thread.
    const f4 a00 = img4[cA.c00 + c];
    const f4 a01 = img4[cA.c01 + c];
    const f4 a10 = img4[cA.c10 + c];
    const f4 a11 = img4[cA.c11 + c];
    const f4 b00 = img4[cB.c00 + c];
    const f4 b01 = img4[cB.c01 + c];
    const f4 b10 = img4[cB.c10 + c];
    const f4 b11 = img4[cB.c11 + c];

    const f4 oA = blend(a00, a01, a10, a11, cA.w00, cA.w01, cA.w10, cA.w11);
    const f4 oB = blend(b00, b01, b10, b11, cB.w00, cB.w01, cB.w10, cB.w11);

    // Output is write-once/never-read: nontemporal to spare L2/L3 for the image.
    __builtin_nontemporal_store(oA, &out4[b0 * CH4 + c]);
    __builtin_nontemporal_store(oB, &out4[b1 * CH4 + c]);
}

extern "C" void kernel_launch(void* const* d_in, const int* in_sizes, int n_in,
                              void* d_out, int out_size, void* d_ws, size_t ws_size,
                              hipStream_t stream) {
    const float* image = (const float*)d_in[0];
    const float* rois  = (const float*)d_in[1];
    float* out = (float*)d_out;

    roi_pool_kernel<<<NBLK, 256, 0, stream>>>(image, rois, out);
}